// Round 3
// baseline (187.015 us; speedup 1.0000x reference)
//
#include <hip/hip_runtime.h>

typedef __bf16 bf16x8 __attribute__((ext_vector_type(8)));
typedef float f32x4 __attribute__((ext_vector_type(4)));
typedef float f32x16 __attribute__((ext_vector_type(16)));

#define MFMA16(a, b, c) __builtin_amdgcn_mfma_f32_16x16x32_bf16(a, b, c, 0, 0, 0)
#define MFMA32(a, b, c) __builtin_amdgcn_mfma_f32_32x32x16_bf16(a, b, c, 0, 0, 0)
#define GLDS16(g, l)                                                              \
  __builtin_amdgcn_global_load_lds((const __attribute__((address_space(1))) void*)(g), \
                                   (__attribute__((address_space(3))) void*)(l), 16, 0, 0)

static __device__ __forceinline__ unsigned cvt_pk_bf16(float lo, float hi) {
  unsigned r;
  asm("v_cvt_pk_bf16_f32 %0, %1, %2" : "=v"(r) : "v"(lo), "v"(hi));
  return r;
}
// v_permlane32_swap_b32: a'[l<32]=a[l], a'[l>=32]=b[l-32], b'[l<32]=a[l+32], b'[l>=32]=b[l]
static __device__ __forceinline__ void permswap(unsigned& a, unsigned& b) {
  asm("v_permlane32_swap_b32 %0, %1" : "+v"(a), "+v"(b));
}

// ---------------- convert f32 -> bf16 (straight) ----------------
__global__ __launch_bounds__(256) void cvt_bf16_kernel(const float* __restrict__ in,
                                                       __bf16* __restrict__ out, int n4) {
  int i = blockIdx.x * 256 + threadIdx.x;
  if (i < n4) {
    float4 v = ((const float4*)in)[i];
    union { __bf16 b[4]; uint2 u; } t;
    t.b[0] = (__bf16)v.x; t.b[1] = (__bf16)v.y;
    t.b[2] = (__bf16)v.z; t.b[3] = (__bf16)v.w;
    ((uint2*)out)[i] = t.u;
  }
}

// ---------------- transpose-convert both weights in one launch ----------------
__global__ __launch_bounds__(256) void transpose_w_kernel(const float* __restrict__ Wq,
                                                          __bf16* __restrict__ WqT,
                                                          const float* __restrict__ Wo,
                                                          __bf16* __restrict__ WoT) {
  const int Kd = 1024;
  int bx = blockIdx.x;
  const float* W; __bf16* WT; int Nd, n0;
  if (bx < 96) { W = Wq; WT = WqT; Nd = 3072; n0 = bx * 32; }
  else         { W = Wo; WT = WoT; Nd = 1024; n0 = (bx - 96) * 32; }
  __shared__ float tile[32][33];
  int k0 = blockIdx.y * 32;
  int tid = threadIdx.x;
  int kk = tid >> 3, nn = (tid & 7) * 4;
  float4 v = *(const float4*)&W[(size_t)(k0 + kk) * Nd + n0 + nn];
  tile[kk][nn] = v.x; tile[kk][nn + 1] = v.y;
  tile[kk][nn + 2] = v.z; tile[kk][nn + 3] = v.w;
  __syncthreads();
  int n2 = tid >> 3, k2 = (tid & 7) * 4;
  union { __bf16 b[4]; uint2 u; } t;
  t.b[0] = (__bf16)tile[k2][n2];
  t.b[1] = (__bf16)tile[k2 + 1][n2];
  t.b[2] = (__bf16)tile[k2 + 2][n2];
  t.b[3] = (__bf16)tile[k2 + 3][n2];
  *(uint2*)&WT[(size_t)(n0 + n2) * Kd + k0 + k2] = t.u;
}

// ---------------- GEMM: C[M,N] = A[M,1024] @ BT[N,1024]^T + bias ----------------
template <bool OUT_F32, int NT>
__global__ __launch_bounds__(256) void gemm_kernel(const __bf16* __restrict__ A,
                                                   const __bf16* __restrict__ BT,
                                                   const float* __restrict__ bias,
                                                   void* __restrict__ Cout, int N,
                                                   int qn, float qs) {
  const int K = 1024;
  const int NJ = NT / 32;
  __shared__ __align__(16) __bf16 As[128 * 32];
  __shared__ __align__(16) __bf16 Bs[NT * 32];
  int tid = threadIdx.x;
  int wave = tid >> 6, lane = tid & 63;
  int quad = lane >> 4, l16 = lane & 15;
  int m0 = blockIdx.x * 128, n0 = blockIdx.y * NT;
  int wm = (wave >> 1) * 64, wn = (wave & 1) * (NT / 2);

  int srow = tid >> 2, scol = (tid & 3) * 8;
  const __bf16* aptr = A + (size_t)(m0 + srow) * K + scol;
  const __bf16* bptr = BT + (size_t)(n0 + srow) * K + scol;
  __bf16* asl = &As[(size_t)wave * 512];
  __bf16* bsl = &Bs[(size_t)wave * 512];

  f32x4 acc[4][NJ] = {};
  for (int k0 = 0; k0 < K; k0 += 32) {
    GLDS16(aptr + k0, asl);
    GLDS16(aptr + (size_t)64 * K + k0, asl + 2048);
    GLDS16(bptr + k0, bsl);
    if (NT == 128) GLDS16(bptr + (size_t)64 * K + k0, bsl + 2048);
    __syncthreads();
    bf16x8 af[4], bf[NJ];
    for (int i = 0; i < 4; i++)
      af[i] = *(bf16x8*)&As[(wm + i * 16 + l16) * 32 + quad * 8];
    for (int j = 0; j < NJ; j++)
      bf[j] = *(bf16x8*)&Bs[(wn + j * 16 + l16) * 32 + quad * 8];
    for (int i = 0; i < 4; i++)
      for (int j = 0; j < NJ; j++)
        acc[i][j] = MFMA16(af[i], bf[j], acc[i][j]);
    __syncthreads();
  }
  for (int j = 0; j < NJ; j++) {
    int col = n0 + wn + j * 16 + l16;
    float bv = bias[col];
    float sc = (col < qn) ? qs : 1.0f;
    for (int i = 0; i < 4; i++) {
      int rowb = m0 + wm + i * 16 + quad * 4;
      for (int r = 0; r < 4; r++) {
        float v = (acc[i][j][r] + bv) * sc;
        if (OUT_F32)
          ((float*)Cout)[(size_t)(rowb + r) * N + col] = v;
        else
          ((__bf16*)Cout)[(size_t)(rowb + r) * N + col] = (__bf16)v;
      }
    }
  }
}

// ---------------- transpose V slice of qkv -> Vt [b][h][d][t] ----------------
__global__ __launch_bounds__(256) void transpose_v_kernel(const __bf16* __restrict__ qkv,
                                                          __bf16* __restrict__ Vt) {
  const int T = 2048, C3 = 3072;
  __shared__ __align__(16) __bf16 tile[64][72];
  int t0 = blockIdx.x * 64;
  int h = blockIdx.y, b = blockIdx.z;
  int tid = threadIdx.x;
  int tt = tid >> 2, c = (tid & 3) * 16;
  const __bf16* src = qkv + (size_t)(b * T + t0 + tt) * C3 + 2048 + h * 64 + c;
  *(uint4*)&tile[tt][c] = *(const uint4*)src;
  *(uint4*)&tile[tt][c + 8] = *(const uint4*)(src + 8);
  __syncthreads();
  int dd = tid >> 2, t2 = (tid & 3) * 16;
  union { __bf16 b_[16]; uint4 u[2]; } o;
  for (int i = 0; i < 16; i++) o.b_[i] = tile[t2 + i][dd];
  __bf16* dst = Vt + ((size_t)(b * 16 + h) * 64 + dd) * T + t0 + t2;
  *(uint4*)dst = o.u[0];
  *(uint4*)(dst + 8) = o.u[1];
}

// ---------------- flash attention: 4 waves x 32 q-rows, pipelined staging ----------------
// Swapped QK^T (S^T = mfma(K,Q)) -> in-register softmax; P -> bf16 A-frags via
// v_cvt_pk_bf16_f32 + v_permlane32_swap_b32 (no P LDS round-trip).
// T4 schedule: 3 LDS buffers, stage tile t+2 each iteration, raw s_barrier with
// counted s_waitcnt vmcnt(4) (never 0 in steady state) -> loads stay in flight
// across barriers. V ds_reads issued before the softmax VALU phase so the LDS
// pipe works under exp2/pack. Row sums on the MFMA pipe (ones-MFMA; lacc rows
// match o rows, so the epilogue needs no cross-lane exchange).
// No-max softmax: Q pre-scaled by 0.125*log2e in GEMM1 epilogue; exp2 directly.
__global__ __launch_bounds__(256, 2) void attn_kernel(const __bf16* __restrict__ qkv,
                                                      const __bf16* __restrict__ Vt,
                                                      __bf16* __restrict__ O) {
  const int T = 2048, C3 = 3072;
  // XCD grouping: linear wg id % 8 == blockIdx.x. Each XCD owns 4 (b,h) pairs
  // (K/V 2 MB resident in its L2); 16 q-blocks of 128 rows per pair.
  int p = blockIdx.x * 4 + (blockIdx.y >> 4);
  int b = p >> 4, h = p & 15;
  int q0 = (blockIdx.y & 15) * 128;

  int tid = threadIdx.x, wave = tid >> 6, lane = tid & 63;
  int l32 = lane & 31, hi = lane >> 5;

  __shared__ __align__(16) __bf16 Ks[3][64 * 64];  // [t][d], 16B-block XOR swizzle
  __shared__ __align__(16) __bf16 Vs[3][64 * 64];  // [d][t], 16B-block XOR swizzle

  // Q B-fragments: lane -> col q = l32, k(d) = ds*16 + hi*8 + i. Loaded once.
  const __bf16* qp = qkv + (size_t)(b * T + q0 + wave * 32 + l32) * C3 + h * 64;
  bf16x8 qf[4];
#pragma unroll
  for (int ds = 0; ds < 4; ds++)
    qf[ds] = *(const bf16x8*)(qp + ds * 16 + hi * 8);

  const __bf16* kbase = qkv + (size_t)(b * T) * C3 + 1024 + h * 64;
  const __bf16* vbase = Vt + (size_t)(b * 16 + h) * 64 * T;

  // Staging: 256 thr x 16B = 4KB per GLDS round; 2 rounds per 64x64 tile (rows
  // +0..31, +32..63). Linear LDS dest (base + lane*16): row = wave*8 + (lane>>3),
  // phys slot = lane&7. Pre-swizzled global source col-block:
  // scb = (lane&7) ^ (row&7); (row&7) == lane>>3 for both rounds.
  int srow = wave * 8 + (lane >> 3);
  int scol = ((lane & 7) ^ (lane >> 3)) * 8;
  const __bf16* ksrc = kbase + (size_t)srow * C3 + scol;
  const __bf16* vsrc = vbase + (size_t)srow * T + scol;

  // Swizzled read offsets (elements), shared formula for K and V tiles:
  // frag [rb][c4]: row = rb*32 + l32, col-block = (c4*2 + hi) ^ (row & 7)
  int off[2][4];
#pragma unroll
  for (int rb = 0; rb < 2; rb++)
#pragma unroll
    for (int c4 = 0; c4 < 4; c4++)
      off[rb][c4] = (rb * 32 + l32) * 64 + (((c4 * 2 + hi) ^ (l32 & 7)) * 8);

  f32x16 o[2] = {};
  f32x16 lacc = {};
  bf16x8 ones;
#pragma unroll
  for (int i = 0; i < 8; i++) ones[i] = (__bf16)1.0f;

  // prologue: stage tiles 0 and 1 (order per tile: K0,K1,V0,V1 -> 4 loads/thread)
  GLDS16(ksrc, &Ks[0][wave * 512]);
  GLDS16(ksrc + (size_t)32 * C3, &Ks[0][wave * 512 + 2048]);
  GLDS16(vsrc, &Vs[0][wave * 512]);
  GLDS16(vsrc + (size_t)32 * T, &Vs[0][wave * 512 + 2048]);
  {
    const __bf16* kp = ksrc + (size_t)64 * C3;
    const __bf16* vp = vsrc + 64;
    GLDS16(kp, &Ks[1][wave * 512]);
    GLDS16(kp + (size_t)32 * C3, &Ks[1][wave * 512 + 2048]);
    GLDS16(vp, &Vs[1][wave * 512]);
    GLDS16(vp + (size_t)32 * T, &Vs[1][wave * 512 + 2048]);
  }

  int cur = 0, st = 2;  // buffer holding tile t; buffer to receive tile t+2
  for (int t = 0; t < 32; ++t) {
    // stage(t) complete; stage(t+1)'s 4 loads stay in flight across the barrier
    if (t < 31)
      asm volatile("s_waitcnt vmcnt(4)" ::: "memory");
    else
      asm volatile("s_waitcnt vmcnt(0)" ::: "memory");
    __builtin_amdgcn_s_barrier();

    if (t + 2 < 32) {  // stage tile t+2 into buffer st (fully read at tile t-1)
      const __bf16* kp = ksrc + (size_t)(t + 2) * 64 * C3;
      const __bf16* vp = vsrc + (t + 2) * 64;
      GLDS16(kp, &Ks[st][wave * 512]);
      GLDS16(kp + (size_t)32 * C3, &Ks[st][wave * 512 + 2048]);
      GLDS16(vp, &Vs[st][wave * 512]);
      GLDS16(vp + (size_t)32 * T, &Vs[st][wave * 512 + 2048]);
    }
    const __bf16* ks = &Ks[cur][0];
    const __bf16* vs = &Vs[cur][0];

    // ---- S^T = mfma(K, Q): D[key][q], lane holds col q=l32, 16 keys per acc reg set
    bf16x8 kf[2][4];
#pragma unroll
    for (int kb = 0; kb < 2; kb++)
#pragma unroll
      for (int ds = 0; ds < 4; ds++)
        kf[kb][ds] = *(const bf16x8*)(ks + off[kb][ds]);
    f32x16 sT[2] = {};
    __builtin_amdgcn_s_setprio(1);
#pragma unroll
    for (int kb = 0; kb < 2; kb++)
#pragma unroll
      for (int ds = 0; ds < 4; ds++)
        sT[kb] = MFMA32(kf[kb][ds], qf[ds], sT[kb]);
    __builtin_amdgcn_s_setprio(0);

    // ---- V frag reads issued BEFORE the softmax VALU phase: LDS pipe fills
    // while the SIMDs run exp2/cvt_pk; lgkmcnt waits land just before PV.
    bf16x8 vf[2][4];
#pragma unroll
    for (int db = 0; db < 2; db++)
#pragma unroll
      for (int ks2 = 0; ks2 < 4; ks2++)
        vf[db][ks2] = *(const bf16x8*)(vs + off[db][ks2]);

    // ---- softmax in-register: p = exp2(s); pack to PV A-frags.
    // acc reg r of sT[kb] holds key k = kb*32 + (r&3) + 8*(r>>2) + 4*hi.
    // ap[ks2] element i must be k = ks2*16 + 8*hi + i:
    //   pair cvt_pk(p[2j],p[2j+1]) with cvt_pk(p[2j+4],p[2j+5]) and permlane32_swap.
    bf16x8 ap[4];
#pragma unroll
    for (int kb = 0; kb < 2; kb++) {
      float pv[16];
#pragma unroll
      for (int r = 0; r < 16; r++) pv[r] = __builtin_amdgcn_exp2f(sT[kb][r]);
#pragma unroll
      for (int hf = 0; hf < 2; hf++) {
        unsigned w0 = cvt_pk_bf16(pv[hf * 8 + 0], pv[hf * 8 + 1]);
        unsigned w1 = cvt_pk_bf16(pv[hf * 8 + 2], pv[hf * 8 + 3]);
        unsigned w2 = cvt_pk_bf16(pv[hf * 8 + 4], pv[hf * 8 + 5]);
        unsigned w3 = cvt_pk_bf16(pv[hf * 8 + 6], pv[hf * 8 + 7]);
        permswap(w0, w2);
        permswap(w1, w3);
        union { unsigned u[4]; bf16x8 v; } pk;
        pk.u[0] = w0; pk.u[1] = w1; pk.u[2] = w2; pk.u[3] = w3;
        ap[kb * 2 + hf] = pk.v;
      }
    }

    // ---- O += P @ V and row sums on the MFMA pipe (ones-MFMA).
    // lacc D-layout rows coincide with o's rows -> epilogue needs no shuffles.
    __builtin_amdgcn_s_setprio(1);
#pragma unroll
    for (int ks2 = 0; ks2 < 4; ks2++) {
      o[0] = MFMA32(ap[ks2], vf[0][ks2], o[0]);
      o[1] = MFMA32(ap[ks2], vf[1][ks2], o[1]);
      lacc = MFMA32(ap[ks2], ones, lacc);
    }
    __builtin_amdgcn_s_setprio(0);

    cur = (cur == 2) ? 0 : cur + 1;
    st = (st == 2) ? 0 : st + 1;
  }

  // ---- epilogue: lacc[r] = rowsum(q-row crow(r,hi)) = o's row r. Divide, store.
  __bf16* ob = O + (size_t)(b * T + q0 + wave * 32) * 1024 + h * 64 + l32;
#pragma unroll
  for (int r = 0; r < 16; r++) {
    float inv = 1.0f / lacc[r];
    int row = (r & 3) + 8 * (r >> 2) + 4 * hi;
    ob[(size_t)row * 1024] = (__bf16)(o[0][r] * inv);
    ob[(size_t)row * 1024 + 32] = (__bf16)(o[1][r] * inv);
  }
}

// ---------------- launch ----------------
extern "C" void kernel_launch(void* const* d_in, const int* in_sizes, int n_in,
                              void* d_out, int out_size, void* d_ws, size_t ws_size,
                              hipStream_t stream) {
  const float* x = (const float*)d_in[0];      // [2,2048,1024]
  const float* W_qkv = (const float*)d_in[1];  // [1024,3072]
  const float* b_qkv = (const float*)d_in[2];  // [3072]
  const float* W_out = (const float*)d_in[3];  // [1024,1024]
  const float* b_out = (const float*)d_in[4];  // [1024]
  float* out = (float*)d_out;                  // [2,2048,1024] f32

  char* ws = (char*)d_ws;
  __bf16* WqkvT = (__bf16*)(ws);               // [3072][1024]  6 MB
  __bf16* WoT = (__bf16*)(ws + 6291456);       // [1024][1024]  2 MB
  __bf16* xb = (__bf16*)(ws + 8388608);        // [4096][1024]  8 MB
  __bf16* qkvb = (__bf16*)(ws + 16777216);     // [4096][3072] 24 MB
  __bf16* Vt = (__bf16*)(ws + 41943040);       // [2][16][64][2048] 8 MB
  __bf16* attnb = xb;  // xb dead after gemm1; reuse for attention output

  const float cs = 0.125f * 1.44269504089f;  // 1/sqrt(64) * log2(e)

  cvt_bf16_kernel<<<4096, 256, 0, stream>>>(x, xb, 1048576);
  transpose_w_kernel<<<dim3(128, 32), 256, 0, stream>>>(W_qkv, WqkvT, W_out, WoT);
  gemm_kernel<false, 128><<<dim3(32, 24), 256, 0, stream>>>(xb, WqkvT, b_qkv, qkvb, 3072,
                                                            1024, cs);
  transpose_v_kernel<<<dim3(32, 16, 2), 256, 0, stream>>>(qkvb, Vt);
  attn_kernel<<<dim3(8, 64), 256, 0, stream>>>(qkvb, Vt, attnb);
  gemm_kernel<true, 64><<<dim3(32, 16), 256, 0, stream>>>(attnb, WoT, b_out, out, 1024,
                                                          0, 1.0f);
}

// Round 4
// 179.140 us; speedup vs baseline: 1.0440x; 1.0440x over previous
//
#include <hip/hip_runtime.h>

typedef __bf16 bf16x8 __attribute__((ext_vector_type(8)));
typedef float f32x4 __attribute__((ext_vector_type(4)));
typedef float f32x16 __attribute__((ext_vector_type(16)));

#define MFMA16(a, b, c) __builtin_amdgcn_mfma_f32_16x16x32_bf16(a, b, c, 0, 0, 0)
#define MFMA32(a, b, c) __builtin_amdgcn_mfma_f32_32x32x16_bf16(a, b, c, 0, 0, 0)
#define GLDS16(g, l)                                                              \
  __builtin_amdgcn_global_load_lds((const __attribute__((address_space(1))) void*)(g), \
                                   (__attribute__((address_space(3))) void*)(l), 16, 0, 0)

static __device__ __forceinline__ unsigned cvt_pk_bf16(float lo, float hi) {
  unsigned r;
  asm("v_cvt_pk_bf16_f32 %0, %1, %2" : "=v"(r) : "v"(lo), "v"(hi));
  return r;
}
// v_permlane32_swap_b32: a'[l<32]=a[l], a'[l>=32]=b[l-32], b'[l<32]=a[l+32], b'[l>=32]=b[l]
static __device__ __forceinline__ void permswap(unsigned& a, unsigned& b) {
  asm("v_permlane32_swap_b32 %0, %1" : "+v"(a), "+v"(b));
}

// ---------------- convert f32 -> bf16 (straight) ----------------
__global__ __launch_bounds__(256) void cvt_bf16_kernel(const float* __restrict__ in,
                                                       __bf16* __restrict__ out, int n4) {
  int i = blockIdx.x * 256 + threadIdx.x;
  if (i < n4) {
    float4 v = ((const float4*)in)[i];
    union { __bf16 b[4]; uint2 u; } t;
    t.b[0] = (__bf16)v.x; t.b[1] = (__bf16)v.y;
    t.b[2] = (__bf16)v.z; t.b[3] = (__bf16)v.w;
    ((uint2*)out)[i] = t.u;
  }
}

// ---------------- transpose-convert both weights in one launch ----------------
__global__ __launch_bounds__(256) void transpose_w_kernel(const float* __restrict__ Wq,
                                                          __bf16* __restrict__ WqT,
                                                          const float* __restrict__ Wo,
                                                          __bf16* __restrict__ WoT) {
  const int Kd = 1024;
  int bx = blockIdx.x;
  const float* W; __bf16* WT; int Nd, n0;
  if (bx < 96) { W = Wq; WT = WqT; Nd = 3072; n0 = bx * 32; }
  else         { W = Wo; WT = WoT; Nd = 1024; n0 = (bx - 96) * 32; }
  __shared__ float tile[32][33];
  int k0 = blockIdx.y * 32;
  int tid = threadIdx.x;
  int kk = tid >> 3, nn = (tid & 7) * 4;
  float4 v = *(const float4*)&W[(size_t)(k0 + kk) * Nd + n0 + nn];
  tile[kk][nn] = v.x; tile[kk][nn + 1] = v.y;
  tile[kk][nn + 2] = v.z; tile[kk][nn + 3] = v.w;
  __syncthreads();
  int n2 = tid >> 3, k2 = (tid & 7) * 4;
  union { __bf16 b[4]; uint2 u; } t;
  t.b[0] = (__bf16)tile[k2][n2];
  t.b[1] = (__bf16)tile[k2 + 1][n2];
  t.b[2] = (__bf16)tile[k2 + 2][n2];
  t.b[3] = (__bf16)tile[k2 + 3][n2];
  *(uint2*)&WT[(size_t)(n0 + n2) * Kd + k0 + k2] = t.u;
}

// ---------------- GEMM: C[M,N] = A[M,1024] @ BT[N,1024]^T + bias ----------------
template <bool OUT_F32, int NT>
__global__ __launch_bounds__(256) void gemm_kernel(const __bf16* __restrict__ A,
                                                   const __bf16* __restrict__ BT,
                                                   const float* __restrict__ bias,
                                                   void* __restrict__ Cout, int N,
                                                   int qn, float qs) {
  const int K = 1024;
  const int NJ = NT / 32;
  __shared__ __align__(16) __bf16 As[128 * 32];
  __shared__ __align__(16) __bf16 Bs[NT * 32];
  int tid = threadIdx.x;
  int wave = tid >> 6, lane = tid & 63;
  int quad = lane >> 4, l16 = lane & 15;
  int m0 = blockIdx.x * 128, n0 = blockIdx.y * NT;
  int wm = (wave >> 1) * 64, wn = (wave & 1) * (NT / 2);

  int srow = tid >> 2, scol = (tid & 3) * 8;
  const __bf16* aptr = A + (size_t)(m0 + srow) * K + scol;
  const __bf16* bptr = BT + (size_t)(n0 + srow) * K + scol;
  __bf16* asl = &As[(size_t)wave * 512];
  __bf16* bsl = &Bs[(size_t)wave * 512];

  f32x4 acc[4][NJ] = {};
  for (int k0 = 0; k0 < K; k0 += 32) {
    GLDS16(aptr + k0, asl);
    GLDS16(aptr + (size_t)64 * K + k0, asl + 2048);
    GLDS16(bptr + k0, bsl);
    if (NT == 128) GLDS16(bptr + (size_t)64 * K + k0, bsl + 2048);
    __syncthreads();
    bf16x8 af[4], bf[NJ];
    for (int i = 0; i < 4; i++)
      af[i] = *(bf16x8*)&As[(wm + i * 16 + l16) * 32 + quad * 8];
    for (int j = 0; j < NJ; j++)
      bf[j] = *(bf16x8*)&Bs[(wn + j * 16 + l16) * 32 + quad * 8];
    for (int i = 0; i < 4; i++)
      for (int j = 0; j < NJ; j++)
        acc[i][j] = MFMA16(af[i], bf[j], acc[i][j]);
    __syncthreads();
  }
  for (int j = 0; j < NJ; j++) {
    int col = n0 + wn + j * 16 + l16;
    float bv = bias[col];
    float sc = (col < qn) ? qs : 1.0f;
    for (int i = 0; i < 4; i++) {
      int rowb = m0 + wm + i * 16 + quad * 4;
      for (int r = 0; r < 4; r++) {
        float v = (acc[i][j][r] + bv) * sc;
        if (OUT_F32)
          ((float*)Cout)[(size_t)(rowb + r) * N + col] = v;
        else
          ((__bf16*)Cout)[(size_t)(rowb + r) * N + col] = (__bf16)v;
      }
    }
  }
}

// ---------------- transpose V slice of qkv -> Vt [b][h][d][t] ----------------
__global__ __launch_bounds__(256) void transpose_v_kernel(const __bf16* __restrict__ qkv,
                                                          __bf16* __restrict__ Vt) {
  const int T = 2048, C3 = 3072;
  __shared__ __align__(16) __bf16 tile[64][72];
  int t0 = blockIdx.x * 64;
  int h = blockIdx.y, b = blockIdx.z;
  int tid = threadIdx.x;
  int tt = tid >> 2, c = (tid & 3) * 16;
  const __bf16* src = qkv + (size_t)(b * T + t0 + tt) * C3 + 2048 + h * 64 + c;
  *(uint4*)&tile[tt][c] = *(const uint4*)src;
  *(uint4*)&tile[tt][c + 8] = *(const uint4*)(src + 8);
  __syncthreads();
  int dd = tid >> 2, t2 = (tid & 3) * 16;
  union { __bf16 b_[16]; uint4 u[2]; } o;
  for (int i = 0; i < 16; i++) o.b_[i] = tile[t2 + i][dd];
  __bf16* dst = Vt + ((size_t)(b * 16 + h) * 64 + dd) * T + t0 + t2;
  *(uint4*)dst = o.u[0];
  *(uint4*)(dst + 8) = o.u[1];
}

// ---------------- flash attention: T15 software-pipelined ----------------
// Swapped QK^T (S^T = mfma(K,Q)); in-register softmax via cvt_pk+permlane32_swap.
// Pipeline: iter t runs QK(t+1) [MFMA] then softmax(t) [VALU] then PV(t) [MFMA] --
// QK(t+1) is independent of softmax(t), so the scheduler overlaps the MFMA pipe
// with the exp2/pack VALU within each wave. sT double-buffered in registers.
// LDS: single arena KV[4] = {K0,V0,K1,V1}, all buffer selection compile-time.
// One __syncthreads per tile; stage(t+2/t+1) issued right after it has a full
// tile of compute to land (L2-hit GLDS ~300cy << tile), so the drain is ~free.
// No-max softmax: Q pre-scaled by 0.125*log2e in GEMM1 epilogue; exp2 directly.
struct AttnState {
  const char* lbase;
  char* wdst;
  int lb[2][4];
};

template <int KRD, int VRD, int KST, int VST, bool DO_KST>
__device__ __forceinline__ void attn_iter(const AttnState& st, const __bf16* kg,
                                          const __bf16* vg, const bf16x8 (&qf)[4],
                                          const f32x16* sIN, f32x16* sOUT, f32x16& o0,
                                          f32x16& o1, float& rs) {
  const int T = 2048, C3 = 3072;
  __syncthreads();  // drains own vmcnt: K(t+1),V(t) landed (all waves) before reads
  if constexpr (DO_KST) {
    GLDS16(kg, st.wdst + KST);
    GLDS16(kg + (size_t)32 * C3, st.wdst + KST + 4096);
  }
  GLDS16(vg, st.wdst + VST);
  GLDS16(vg + (size_t)32 * T, st.wdst + VST + 4096);

  // K(t+1) fragments + V(t) fragments (V issued early; consumed at PV)
  bf16x8 kf[2][4], vf[2][4];
#pragma unroll
  for (int rb = 0; rb < 2; rb++)
#pragma unroll
    for (int ds = 0; ds < 4; ds++)
      kf[rb][ds] = *(const bf16x8*)(st.lbase + st.lb[rb][ds] + KRD);
#pragma unroll
  for (int db = 0; db < 2; db++)
#pragma unroll
    for (int k2 = 0; k2 < 4; k2++)
      vf[db][k2] = *(const bf16x8*)(st.lbase + st.lb[db][k2] + VRD);

  // QK(t+1): independent of softmax(t) below -> MFMA/VALU overlap
  f32x16 s0 = {}, s1 = {};
#pragma unroll
  for (int ds = 0; ds < 4; ds++) {
    s0 = MFMA32(kf[0][ds], qf[ds], s0);
    s1 = MFMA32(kf[1][ds], qf[ds], s1);
  }
  sOUT[0] = s0;
  sOUT[1] = s1;

  // softmax(t): p = exp2(sIN); rowsum; pack to PV A-frags.
  // acc reg r of sIN[kb] holds key k = kb*32 + (r&3) + 8*(r>>2) + 4*hi.
  // ap[k2] element i must be k = k2*16 + 8*hi + i: pair cvt_pk(p[2j],p[2j+1])
  // with cvt_pk(p[2j+4],p[2j+5]) and permlane32_swap.
  bf16x8 ap[4];
#pragma unroll
  for (int kb = 0; kb < 2; kb++) {
    float pv[16];
#pragma unroll
    for (int r = 0; r < 16; r++) {
      pv[r] = __builtin_amdgcn_exp2f(sIN[kb][r]);
      rs += pv[r];
    }
#pragma unroll
    for (int hf = 0; hf < 2; hf++) {
      unsigned w0 = cvt_pk_bf16(pv[hf * 8 + 0], pv[hf * 8 + 1]);
      unsigned w1 = cvt_pk_bf16(pv[hf * 8 + 2], pv[hf * 8 + 3]);
      unsigned w2 = cvt_pk_bf16(pv[hf * 8 + 4], pv[hf * 8 + 5]);
      unsigned w3 = cvt_pk_bf16(pv[hf * 8 + 6], pv[hf * 8 + 7]);
      permswap(w0, w2);
      permswap(w1, w3);
      union { unsigned u[4]; bf16x8 v; } pk;
      pk.u[0] = w0; pk.u[1] = w1; pk.u[2] = w2; pk.u[3] = w3;
      ap[kb * 2 + hf] = pk.v;
    }
  }

  // PV(t)
#pragma unroll
  for (int k2 = 0; k2 < 4; k2++) {
    o0 = MFMA32(ap[k2], vf[0][k2], o0);
    o1 = MFMA32(ap[k2], vf[1][k2], o1);
  }
}

__global__ __launch_bounds__(256, 2) void attn_kernel(const __bf16* __restrict__ qkv,
                                                      const __bf16* __restrict__ Vt,
                                                      __bf16* __restrict__ O) {
  const int T = 2048, C3 = 3072;
  // XCD grouping: linear wg id % 8 == blockIdx.x. Each XCD owns 4 (b,h) pairs
  // (K/V resident in its L2); 16 q-blocks of 128 rows per pair.
  int p = blockIdx.x * 4 + (blockIdx.y >> 4);
  int b = p >> 4, h = p & 15;
  int q0 = (blockIdx.y & 15) * 128;

  int tid = threadIdx.x, wave = tid >> 6, lane = tid & 63;
  int l32 = lane & 31, hi = lane >> 5;

  // LDS arena: K0 @0, V0 @8192, K1 @16384, V1 @24576 (bytes). 32 KB total.
  __shared__ __align__(16) __bf16 KV[4][64 * 64];

  // Q B-fragments: lane -> col q = l32, k(d) = ds*16 + hi*8 + i. Loaded once.
  const __bf16* qp = qkv + (size_t)(b * T + q0 + wave * 32 + l32) * C3 + h * 64;
  bf16x8 qf[4];
#pragma unroll
  for (int ds = 0; ds < 4; ds++)
    qf[ds] = *(const bf16x8*)(qp + ds * 16 + hi * 8);

  const __bf16* kbase = qkv + (size_t)(b * T) * C3 + 1024 + h * 64;
  const __bf16* vbase = Vt + (size_t)(b * 16 + h) * 64 * T;

  // Staging: 256 thr x 16B = 4KB per GLDS round; 2 rounds per 64x64 tile.
  // Linear LDS dest (wave-uniform base + lane*16): row = wave*8 + (lane>>3),
  // phys slot = lane&7. Pre-swizzled global source col-block:
  // scb = (lane&7) ^ (row&7); (row&7) == lane>>3 for both rounds.
  int srow = wave * 8 + (lane >> 3);
  int scol = ((lane & 7) ^ (lane >> 3)) * 8;
  const __bf16* ksrc = kbase + (size_t)srow * C3 + scol;
  const __bf16* vsrc = vbase + (size_t)srow * T + scol;

  AttnState st;
  st.lbase = (const char*)&KV[0][0];
  st.wdst = (char*)&KV[0][0] + wave * 1024;
  // Swizzled read byte-offsets within one tile buffer:
  // frag [rb][c4]: row = rb*32 + l32, col-block = (c4*2 + hi) ^ (row & 7)
#pragma unroll
  for (int rb = 0; rb < 2; rb++)
#pragma unroll
    for (int c4 = 0; c4 < 4; c4++)
      st.lb[rb][c4] =
          ((rb * 32 + l32) * 64 + (((c4 * 2 + hi) ^ (l32 & 7)) * 8)) * 2;

  f32x16 o0 = {}, o1 = {};
  f32x16 sA[2], sB[2];
  float rs = 0.0f;

  // prologue: stage K(0)->K0, V(0)->V0, K(1)->K1
  GLDS16(ksrc, st.wdst + 0);
  GLDS16(ksrc + (size_t)32 * C3, st.wdst + 4096);
  GLDS16(vsrc, st.wdst + 8192);
  GLDS16(vsrc + (size_t)32 * T, st.wdst + 8192 + 4096);
  GLDS16(ksrc + (size_t)64 * C3, st.wdst + 16384);
  GLDS16(ksrc + (size_t)96 * C3, st.wdst + 16384 + 4096);
  __syncthreads();

  // QK(0) from K0 -> sA
  {
    bf16x8 kf[2][4];
#pragma unroll
    for (int rb = 0; rb < 2; rb++)
#pragma unroll
      for (int ds = 0; ds < 4; ds++)
        kf[rb][ds] = *(const bf16x8*)(st.lbase + st.lb[rb][ds] + 0);
    f32x16 s0 = {}, s1 = {};
#pragma unroll
    for (int ds = 0; ds < 4; ds++) {
      s0 = MFMA32(kf[0][ds], qf[ds], s0);
      s1 = MFMA32(kf[1][ds], qf[ds], s1);
    }
    sA[0] = s0;
    sA[1] = s1;
  }

  const size_t kstep = (size_t)64 * C3;
  const __bf16* kg = ksrc + 2 * kstep;  // K(t+2) source for t=0
  const __bf16* vg = vsrc + 64;         // V(t+1) source for t=0

  // iters t=0..29 (15 even/odd pairs), t=30 (no K stage), tail t=31
  for (int tp = 0; tp < 15; ++tp) {
    // even t: read K(t+1) from K1(16384), V(t) from V0(8192);
    //         stage K(t+2)->K0(0), V(t+1)->V1(24576)
    attn_iter<16384, 8192, 0, 24576, true>(st, kg, vg, qf, sA, sB, o0, o1, rs);
    kg += kstep; vg += 64;
    // odd t: read K from K0, V from V1; stage K->K1, V->V0
    attn_iter<0, 24576, 16384, 8192, true>(st, kg, vg, qf, sB, sA, o0, o1, rs);
    kg += kstep; vg += 64;
  }
  // t=30 (even): stage only V(31)->V1
  attn_iter<16384, 8192, 0, 24576, false>(st, kg, vg, qf, sA, sB, o0, o1, rs);

  // tail t=31: softmax(sB), PV from V1
  {
    __syncthreads();
    bf16x8 vf[2][4];
#pragma unroll
    for (int db = 0; db < 2; db++)
#pragma unroll
      for (int k2 = 0; k2 < 4; k2++)
        vf[db][k2] = *(const bf16x8*)(st.lbase + st.lb[db][k2] + 24576);
    bf16x8 ap[4];
#pragma unroll
    for (int kb = 0; kb < 2; kb++) {
      float pv[16];
#pragma unroll
      for (int r = 0; r < 16; r++) {
        pv[r] = __builtin_amdgcn_exp2f(sB[kb][r]);
        rs += pv[r];
      }
#pragma unroll
      for (int hf = 0; hf < 2; hf++) {
        unsigned w0 = cvt_pk_bf16(pv[hf * 8 + 0], pv[hf * 8 + 1]);
        unsigned w1 = cvt_pk_bf16(pv[hf * 8 + 2], pv[hf * 8 + 3]);
        unsigned w2 = cvt_pk_bf16(pv[hf * 8 + 4], pv[hf * 8 + 5]);
        unsigned w3 = cvt_pk_bf16(pv[hf * 8 + 6], pv[hf * 8 + 7]);
        permswap(w0, w2);
        permswap(w1, w3);
        union { unsigned u[4]; bf16x8 v; } pk;
        pk.u[0] = w0; pk.u[1] = w1; pk.u[2] = w2; pk.u[3] = w3;
        ap[kb * 2 + hf] = pk.v;
      }
    }
#pragma unroll
    for (int k2 = 0; k2 < 4; k2++) {
      o0 = MFMA32(ap[k2], vf[0][k2], o0);
      o1 = MFMA32(ap[k2], vf[1][k2], o1);
    }
  }

  // ---- epilogue: finish row sums (exchange halves), divide, store
  unsigned xu = __float_as_uint(rs), yu = __float_as_uint(rs);
  permswap(xu, yu);
  float inv = 1.0f / (__uint_as_float(xu) + __uint_as_float(yu));  // rowsum for q=l32
  float invv[16];
#pragma unroll
  for (int r = 0; r < 16; r++)
    invv[r] = __shfl(inv, (r & 3) + 8 * (r >> 2) + 4 * hi);

  __bf16* ob = O + (size_t)(b * T + q0 + wave * 32) * 1024 + h * 64 + l32;
#pragma unroll
  for (int r = 0; r < 16; r++) {
    int row = (r & 3) + 8 * (r >> 2) + 4 * hi;
    ob[(size_t)row * 1024] = (__bf16)(o0[r] * invv[r]);
    ob[(size_t)row * 1024 + 32] = (__bf16)(o1[r] * invv[r]);
  }
}

// ---------------- launch ----------------
extern "C" void kernel_launch(void* const* d_in, const int* in_sizes, int n_in,
                              void* d_out, int out_size, void* d_ws, size_t ws_size,
                              hipStream_t stream) {
  const float* x = (const float*)d_in[0];      // [2,2048,1024]
  const float* W_qkv = (const float*)d_in[1];  // [1024,3072]
  const float* b_qkv = (const float*)d_in[2];  // [3072]
  const float* W_out = (const float*)d_in[3];  // [1024,1024]
  const float* b_out = (const float*)d_in[4];  // [1024]
  float* out = (float*)d_out;                  // [2,2048,1024] f32

  char* ws = (char*)d_ws;
  __bf16* WqkvT = (__bf16*)(ws);               // [3072][1024]  6 MB
  __bf16* WoT = (__bf16*)(ws + 6291456);       // [1024][1024]  2 MB
  __bf16* xb = (__bf16*)(ws + 8388608);        // [4096][1024]  8 MB
  __bf16* qkvb = (__bf16*)(ws + 16777216);     // [4096][3072] 24 MB
  __bf16* Vt = (__bf16*)(ws + 41943040);       // [2][16][64][2048] 8 MB
  __bf16* attnb = xb;  // xb dead after gemm1; reuse for attention output

  const float cs = 0.125f * 1.44269504089f;  // 1/sqrt(64) * log2(e)

  cvt_bf16_kernel<<<4096, 256, 0, stream>>>(x, xb, 1048576);
  transpose_w_kernel<<<dim3(128, 32), 256, 0, stream>>>(W_qkv, WqkvT, W_out, WoT);
  gemm_kernel<false, 128><<<dim3(32, 24), 256, 0, stream>>>(xb, WqkvT, b_qkv, qkvb, 3072,
                                                            1024, cs);
  transpose_v_kernel<<<dim3(32, 16, 2), 256, 0, stream>>>(qkvb, Vt);
  attn_kernel<<<dim3(8, 64), 256, 0, stream>>>(qkvb, Vt, attnb);
  gemm_kernel<true, 64><<<dim3(32, 16), 256, 0, stream>>>(attnb, WoT, b_out, out, 1024,
                                                          0, 1.0f);
}